// Round 4
// baseline (244.769 us; speedup 1.0000x reference)
//
#include <hip/hip_runtime.h>
#include <math.h>

#define G_GENES 2000
#define C_CELLS 128
#define H_DIM   256
#define CE_DIM  64
#define LDAe    264   // x1t row stride in bf16 elems (256 + 8 pad)

typedef __attribute__((ext_vector_type(8))) short short8;
typedef __attribute__((ext_vector_type(4))) float floatx4;

__device__ __forceinline__ float eluf(float x) {
    float e = __expf(x) - 1.0f;
    return x > 0.0f ? x : e;
}
__device__ __forceinline__ unsigned short f2bf(float v) {
    unsigned u = __float_as_uint(v);
    u += 0x7FFF + ((u >> 16) & 1);       // RNE
    return (unsigned short)(u >> 16);
}

// ---------------------------------------------------------------------------
// K1a: split-K partials of hid_pre[c][h] = ctrl[c,:] @ ce_w1[:,h]
// grid = 128 cells * 16 k-chunks (125 k each), 256 threads (t = h).
// ---------------------------------------------------------------------------
__global__ __launch_bounds__(256) void k1a(
    const float* __restrict__ ctrl, const float* __restrict__ ce_w1,
    float* __restrict__ hidpart)
{
    __shared__ float crow[125];
    const int c  = blockIdx.x >> 4;
    const int kc = blockIdx.x & 15;
    const int t  = threadIdx.x;

    if (t < 125) crow[t] = ctrl[(size_t)c * G_GENES + kc * 125 + t];
    __syncthreads();

    float s = 0.f;
    const float* w = ce_w1 + (size_t)(kc * 125) * H_DIM + t;
    #pragma unroll 5
    for (int k = 0; k < 125; ++k) s = fmaf(crow[k], w[(size_t)k * H_DIM], s);
    hidpart[((size_t)c * 16 + kc) * H_DIM + t] = s;
}

// ---------------------------------------------------------------------------
// K1b: hid=elu(sum parts + b1); cel=hid@ce_w2+b2; Atc[c][h]=cel@g_w1[1:65,h]
// grid = 128 cells, 256 threads, no divergent long loops.
// ---------------------------------------------------------------------------
__global__ __launch_bounds__(256) void k1b(
    const float* __restrict__ hidpart, const float* __restrict__ ce_b1,
    const float* __restrict__ ce_w2, const float* __restrict__ ce_b2,
    const float* __restrict__ g_w1, float* __restrict__ Atc)
{
    __shared__ float hid[H_DIM];
    __shared__ float celp[4 * CE_DIM];
    __shared__ float cel[CE_DIM];
    const int c = blockIdx.x;
    const int t = threadIdx.x;

    float s = ce_b1[t];
    #pragma unroll
    for (int p = 0; p < 16; ++p) s += hidpart[((size_t)c * 16 + p) * H_DIM + t];
    hid[t] = eluf(s);
    __syncthreads();

    {   // cel partials: e = t&63, quarter q4 = t>>6 covers 64 h each
        const int e = t & 63, q4 = t >> 6;
        float cp = 0.f;
        const float* w2 = ce_w2 + (size_t)(q4 * 64) * CE_DIM + e;
        #pragma unroll 8
        for (int h = 0; h < 64; ++h) cp = fmaf(hid[q4 * 64 + h], w2[(size_t)h * CE_DIM], cp);
        celp[q4 * CE_DIM + e] = cp;
    }
    __syncthreads();
    if (t < CE_DIM)
        cel[t] = ce_b2[t] + celp[t] + celp[CE_DIM + t] + celp[2 * CE_DIM + t] + celp[3 * CE_DIM + t];
    __syncthreads();

    float a = 0.f;
    #pragma unroll 8
    for (int e = 0; e < CE_DIM; ++e) a = fmaf(cel[e], g_w1[(size_t)(1 + e) * H_DIM + t], a);
    Atc[(size_t)c * H_DIM + t] = a;
}

// ---------------------------------------------------------------------------
// K0: w2abt[n][k] = bf16(g_w2[k][n]) for k<256 (W2a half, transposed)
// ---------------------------------------------------------------------------
__global__ __launch_bounds__(256) void k_w2abt(
    const float* __restrict__ g_w2, unsigned short* __restrict__ w2abt)
{
    const int n = blockIdx.x;
    const int k = threadIdx.x;
    w2abt[(size_t)n * H_DIM + k] = f2bf(g_w2[(size_t)k * H_DIM + n]);
}

// ---------------------------------------------------------------------------
// K_pqb: per gene g (2000 blocks, 256 threads, tiny LDS -> high occupancy):
//   Bvg[g][h] = b1[h] + 128*w1[130,h] + shift*w1[129,h] + ge@w1[65:129,h]
//   p[h]      = (1/128) sum_c elu(cc[c]*w1[0,h] + Atc[c,h] + Bvg[g,h])  (fp32)
//   q_all[g][j] = p @ W2b[:,j] + b2[j]
// ---------------------------------------------------------------------------
__global__ __launch_bounds__(256) void k_pqb(
    const float* __restrict__ ctrl, const float* __restrict__ shiftv,
    const int* __restrict__ gidx, const float* __restrict__ gtab,
    const float* __restrict__ g_w1, const float* __restrict__ g_b1,
    const float* __restrict__ g_w2, const float* __restrict__ g_b2,
    const float* __restrict__ Atc, float* __restrict__ Bvg,
    float* __restrict__ q_all)
{
    __shared__ float cc[C_CELLS];
    __shared__ float gt[CE_DIM];
    __shared__ float pvec[H_DIM];

    const int g = blockIdx.x;
    const int t = threadIdx.x;
    const int idx = gidx[g];

    if (t < C_CELLS) cc[t] = ctrl[(size_t)t * G_GENES + idx];
    else if (t < C_CELLS + CE_DIM) gt[t - C_CELLS] = gtab[(size_t)idx * CE_DIM + (t - C_CELLS)];
    __syncthreads();

    const float w1r0 = g_w1[t];
    float bv = g_b1[t] + 128.0f * g_w1[(size_t)130 * H_DIM + t]
             + shiftv[idx] * g_w1[(size_t)129 * H_DIM + t];
    #pragma unroll 8
    for (int e = 0; e < CE_DIM; ++e) bv = fmaf(gt[e], g_w1[(size_t)(65 + e) * H_DIM + t], bv);
    Bvg[(size_t)g * H_DIM + t] = bv;

    float s = 0.f;
    #pragma unroll 4
    for (int c = 0; c < C_CELLS; ++c)
        s += eluf(fmaf(cc[c], w1r0, Atc[(size_t)c * H_DIM + t] + bv));
    pvec[t] = s * (1.0f / 128.0f);
    __syncthreads();

    float q = g_b2[t];
    const float* w2b = g_w2 + (size_t)H_DIM * H_DIM + t;
    #pragma unroll 8
    for (int h = 0; h < H_DIM; ++h) q = fmaf(pvec[h], w2b[(size_t)h * H_DIM], q);
    q_all[(size_t)g * H_DIM + t] = q;
}

// ---------------------------------------------------------------------------
// K_main: one block per gene, 512 threads = 8 waves (2m x 4n wave grid).
// Slim: x1 build -> MFMA -> epilogue -> softmax. 5 barriers.
// ---------------------------------------------------------------------------
__global__ __launch_bounds__(512, 4) void k_main(
    const float* __restrict__ ctrl, const int* __restrict__ gidx,
    const float* __restrict__ g_w1, const float* __restrict__ g_w3,
    const float* __restrict__ Atc, const float* __restrict__ Bvg,
    const float* __restrict__ q_all, const unsigned short* __restrict__ w2abt,
    float* __restrict__ out)
{
    __shared__ __align__(16) unsigned short x1t[C_CELLS * LDAe];  // 67584 B
    __shared__ float cc[C_CELLS];
    __shared__ float qv[H_DIM];
    __shared__ float w3v[H_DIM];
    __shared__ __align__(16) float Bvl[H_DIM];
    __shared__ __align__(16) float w1l[H_DIM];
    __shared__ float red2[C_CELLS * 5];
    __shared__ float wred[4];

    const int g = blockIdx.x;
    const int t = threadIdx.x;
    const int idx = gidx[g];

    if (t < C_CELLS) cc[t] = ctrl[(size_t)t * G_GENES + idx];
    if (t < H_DIM) {
        qv[t]  = q_all[(size_t)g * H_DIM + t];
        w3v[t] = g_w3[t];
    } else {
        const int u = t - H_DIM;
        Bvl[u] = Bvg[(size_t)g * H_DIM + u];
        w1l[u] = g_w1[u];
    }
    __syncthreads();   // B0

    // ---- x1 build: thread = (cell = t>>2, h-quarter = t&3), 64 h each ----
    {
        const int xc = t >> 2;
        const int xh = (t & 3) * 64;
        const float ccv = cc[xc];
        #pragma unroll
        for (int i = 0; i < 8; ++i) {
            const int h0 = xh + i * 8;
            float4 at0 = *(const float4*)(Atc + (size_t)xc * H_DIM + h0);
            float4 at1 = *(const float4*)(Atc + (size_t)xc * H_DIM + h0 + 4);
            float4 bv0 = *(const float4*)(Bvl + h0);
            float4 bv1 = *(const float4*)(Bvl + h0 + 4);
            float4 wr0 = *(const float4*)(w1l + h0);
            float4 wr1 = *(const float4*)(w1l + h0 + 4);
            float v0 = eluf(fmaf(ccv, wr0.x, at0.x + bv0.x));
            float v1 = eluf(fmaf(ccv, wr0.y, at0.y + bv0.y));
            float v2 = eluf(fmaf(ccv, wr0.z, at0.z + bv0.z));
            float v3 = eluf(fmaf(ccv, wr0.w, at0.w + bv0.w));
            float v4 = eluf(fmaf(ccv, wr1.x, at1.x + bv1.x));
            float v5 = eluf(fmaf(ccv, wr1.y, at1.y + bv1.y));
            float v6 = eluf(fmaf(ccv, wr1.z, at1.z + bv1.z));
            float v7 = eluf(fmaf(ccv, wr1.w, at1.w + bv1.w));
            uint4 pk;
            pk.x = (unsigned)f2bf(v0) | ((unsigned)f2bf(v1) << 16);
            pk.y = (unsigned)f2bf(v2) | ((unsigned)f2bf(v3) << 16);
            pk.z = (unsigned)f2bf(v4) | ((unsigned)f2bf(v5) << 16);
            pk.w = (unsigned)f2bf(v6) | ((unsigned)f2bf(v7) << 16);
            *(uint4*)&x1t[xc * LDAe + h0] = pk;
        }
    }
    __syncthreads();   // B1: x1t complete

    const int lane = t & 63;
    const int w    = t >> 6;
    const int quad = lane >> 4;
    const int nlo  = lane & 15;
    const int wm   = w >> 2;      // rows [wm*64, +64)
    const int wn   = w & 3;       // cols [wn*64, +64)

    floatx4 acc[4][4];
    #pragma unroll
    for (int mt = 0; mt < 4; ++mt)
        #pragma unroll
        for (int nt = 0; nt < 4; ++nt)
            acc[mt][nt] = (floatx4){0.f, 0.f, 0.f, 0.f};

    const unsigned short* bbase = w2abt + (size_t)(wn * 64 + nlo) * H_DIM + quad * 8;
    const unsigned short* abase = &x1t[(wm * 64 + nlo) * LDAe + quad * 8];

    for (int kt = 0; kt < 8; ++kt) {
        short8 af[4];
        #pragma unroll
        for (int mt = 0; mt < 4; ++mt)
            af[mt] = *(const short8*)(abase + mt * 16 * LDAe + kt * 32);
        #pragma unroll
        for (int nt = 0; nt < 4; ++nt) {
            short8 bf = *(const short8*)(bbase + (size_t)nt * 16 * H_DIM + kt * 32);
            #pragma unroll
            for (int mt = 0; mt < 4; ++mt)
                acc[mt][nt] = __builtin_amdgcn_mfma_f32_16x16x32_bf16(af[mt], bf, acc[mt][nt], 0, 0, 0);
        }
    }

    // ---- epilogue (no barrier needed: qv/w3v ready since B0) ----
    float qj[4], w3j[4];
    #pragma unroll
    for (int nt = 0; nt < 4; ++nt) {
        const int j = wn * 64 + nt * 16 + nlo;
        qj[nt] = qv[j];
        w3j[nt] = w3v[j];
    }
    #pragma unroll
    for (int mt = 0; mt < 4; ++mt) {
        #pragma unroll
        for (int reg = 0; reg < 4; ++reg) {
            float part = 0.f;
            #pragma unroll
            for (int nt = 0; nt < 4; ++nt)
                part = fmaf(eluf(acc[mt][nt][reg] + qj[nt]), w3j[nt], part);
            part += __shfl_xor(part, 1);
            part += __shfl_xor(part, 2);
            part += __shfl_xor(part, 4);
            part += __shfl_xor(part, 8);
            if (nlo == 0)
                red2[(wm * 64 + mt * 16 + quad * 4 + reg) * 5 + wn] = part;
        }
    }
    __syncthreads();   // B2: red2 complete

    // ---- softmax over 128 cells (waves 0-1, shuffle-based) ----
    float s = 0.f, e = 0.f;
    if (t < C_CELLS) {
        s = red2[t * 5 + 0] + red2[t * 5 + 1] + red2[t * 5 + 2] + red2[t * 5 + 3];
        float m = s;
        #pragma unroll
        for (int off = 1; off < 64; off <<= 1) m = fmaxf(m, __shfl_xor(m, off));
        if (lane == 0) wred[w] = m;
    }
    __syncthreads();   // B3
    if (t < C_CELLS) {
        const float m = fmaxf(wred[0], wred[1]);
        e = __expf(s - m);
        float S = e;
        #pragma unroll
        for (int off = 1; off < 64; off <<= 1) S += __shfl_xor(S, off);
        if (lane == 0) wred[2 + w] = S;
    }
    __syncthreads();   // B4
    if (t < C_CELLS) out[(size_t)t * G_GENES + g] = e / (wred[2] + wred[3]);
}

// ---------------------------------------------------------------------------
extern "C" void kernel_launch(void* const* d_in, const int* in_sizes, int n_in,
                              void* d_out, int out_size, void* d_ws, size_t ws_size,
                              hipStream_t stream) {
    const float* ctrl   = (const float*)d_in[0];
    const float* shiftv = (const float*)d_in[1];
    const int*   gidx   = (const int*)d_in[2];
    const float* ce_w1  = (const float*)d_in[3];
    const float* ce_b1  = (const float*)d_in[4];
    const float* ce_w2  = (const float*)d_in[5];
    const float* ce_b2  = (const float*)d_in[6];
    const float* gtab   = (const float*)d_in[7];
    const float* g_w1   = (const float*)d_in[8];
    const float* g_b1   = (const float*)d_in[9];
    const float* g_w2   = (const float*)d_in[10];
    const float* g_b2   = (const float*)d_in[11];
    const float* g_w3   = (const float*)d_in[12];
    // g_b3 and the p2@w3b term are per-gene constants: cancel in softmax.

    // workspace layout (4.25 MB):
    //   [0,128K)       Atc       128x256 f32
    //   [128K,256K)    w2abt     256x256 bf16
    //   [256K,2.25M)   Bvg       2000x256 f32
    //   [2.25M,4.25M)  q_all     2000x256 f32  (first used as hidpart 128x16x256 f32)
    char* ws = (char*)d_ws;
    float* Atc            = (float*)(ws);
    unsigned short* w2abt = (unsigned short*)(ws + 128 * 1024);
    float* Bvg            = (float*)(ws + 256 * 1024);
    float* q_all          = (float*)(ws + 256 * 1024 + (size_t)G_GENES * H_DIM * 4);
    float* hidpart        = q_all;   // aliased: consumed by k1b before k_pqb writes q_all
    float* out            = (float*)d_out;

    k1a<<<C_CELLS * 16, 256, 0, stream>>>(ctrl, ce_w1, hidpart);
    k_w2abt<<<H_DIM, 256, 0, stream>>>(g_w2, w2abt);
    k1b<<<C_CELLS, 256, 0, stream>>>(hidpart, ce_b1, ce_w2, ce_b2, g_w1, Atc);
    k_pqb<<<G_GENES, 256, 0, stream>>>(ctrl, shiftv, gidx, gtab, g_w1, g_b1, g_w2, g_b2,
                                       Atc, Bvg, q_all);
    k_main<<<G_GENES, 512, 0, stream>>>(ctrl, gidx, g_w1, g_w3, Atc, Bvg, q_all, w2abt, out);
}

// Round 5
// 217.906 us; speedup vs baseline: 1.1233x; 1.1233x over previous
//
#include <hip/hip_runtime.h>
#include <math.h>

#define G_GENES 2000
#define C_CELLS 128
#define H_DIM   256
#define CE_DIM  64
#define LDAe    260   // x1t row stride (bf16 elems): 130 dwords = 2 mod 32 -> conflict-free

typedef __attribute__((ext_vector_type(8))) short short8;
typedef __attribute__((ext_vector_type(4))) float floatx4;

__device__ __forceinline__ float eluf(float x) {
    float e = __expf(x) - 1.0f;
    return x > 0.0f ? x : e;
}
__device__ __forceinline__ unsigned short f2bf(float v) {
    unsigned u = __float_as_uint(v);
    u += 0x7FFF + ((u >> 16) & 1);       // RNE
    return (unsigned short)(u >> 16);
}

// ---------------------------------------------------------------------------
// K_prep: one kernel, three block roles (636 blocks x 1024 threads):
//  blocks [0,128):    per-cell ce-MLP -> Atc[c][h]   (split-K x4 in-block)
//  blocks [128,136):  w2abt[n][k] = bf16(g_w2[k][n]), k<256
//  blocks [136,636):  Bvg[g][h] per-gene bias row (4 genes/block)
// ---------------------------------------------------------------------------
__global__ __launch_bounds__(1024) void k_prep(
    const float* __restrict__ ctrl, const float* __restrict__ ce_w1,
    const float* __restrict__ ce_b1, const float* __restrict__ ce_w2,
    const float* __restrict__ ce_b2, const float* __restrict__ g_w1,
    const float* __restrict__ g_b1, const float* __restrict__ shiftv,
    const int* __restrict__ gidx, const float* __restrict__ gtab,
    const float* __restrict__ g_w2,
    float* __restrict__ Atc, unsigned short* __restrict__ w2abt,
    float* __restrict__ Bvg)
{
    const int b = blockIdx.x;
    const int t = threadIdx.x;

    if (b < C_CELLS) {
        __shared__ float crow[G_GENES];
        __shared__ float hidp[4][H_DIM];
        __shared__ float hid[H_DIM];
        __shared__ float celp[16 * CE_DIM];
        __shared__ float cel[CE_DIM];
        const int c = b;
        for (int i = t; i < G_GENES; i += 1024) crow[i] = ctrl[(size_t)c * G_GENES + i];
        __syncthreads();

        {   // hid_pre partials: h = t&255, k-quarter kq = t>>8 (500 k each), 10-way ILP
            const int h = t & 255, kq = t >> 8;
            float s[10];
            #pragma unroll
            for (int j = 0; j < 10; ++j) s[j] = 0.f;
            const float* w = ce_w1 + (size_t)(kq * 500) * H_DIM + h;
            const float* cr = crow + kq * 500;
            for (int k0 = 0; k0 < 50; ++k0) {
                #pragma unroll
                for (int j = 0; j < 10; ++j)
                    s[j] = fmaf(cr[k0 * 10 + j], w[(size_t)(k0 * 10 + j) * H_DIM], s[j]);
            }
            float ss = 0.f;
            #pragma unroll
            for (int j = 0; j < 10; ++j) ss += s[j];
            hidp[kq][h] = ss;
        }
        __syncthreads();
        if (t < H_DIM)
            hid[t] = eluf(hidp[0][t] + hidp[1][t] + hidp[2][t] + hidp[3][t] + ce_b1[t]);
        __syncthreads();

        {   // cel partials: e = t&63, 16 h-groups of 16
            const int e = t & 63, grp = t >> 6;
            float cp = 0.f;
            #pragma unroll
            for (int hh = 0; hh < 16; ++hh)
                cp = fmaf(hid[grp * 16 + hh], ce_w2[(size_t)(grp * 16 + hh) * CE_DIM + e], cp);
            celp[grp * CE_DIM + e] = cp;
        }
        __syncthreads();
        if (t < CE_DIM) {
            float s = ce_b2[t];
            #pragma unroll
            for (int grp = 0; grp < 16; ++grp) s += celp[grp * CE_DIM + t];
            cel[t] = s;
        }
        __syncthreads();
        if (t < H_DIM) {
            float a = 0.f;
            #pragma unroll 8
            for (int e = 0; e < CE_DIM; ++e) a = fmaf(cel[e], g_w1[(size_t)(1 + e) * H_DIM + t], a);
            Atc[(size_t)c * H_DIM + t] = a;
        }
    } else if (b < C_CELLS + 8) {
        const int n  = (b - C_CELLS) * 32 + (t >> 5);
        const int k0 = (t & 31) * 8;
        unsigned v[8];
        #pragma unroll
        for (int j = 0; j < 8; ++j) v[j] = f2bf(g_w2[(size_t)(k0 + j) * H_DIM + n]);
        uint4 pk;
        pk.x = v[0] | (v[1] << 16);
        pk.y = v[2] | (v[3] << 16);
        pk.z = v[4] | (v[5] << 16);
        pk.w = v[6] | (v[7] << 16);
        *(uint4*)&w2abt[(size_t)n * H_DIM + k0] = pk;
    } else {
        const int g = (b - C_CELLS - 8) * 4 + (t >> 8);
        const int h = t & 255;
        const int idx = gidx[g];
        float bv = g_b1[h] + 128.0f * g_w1[(size_t)130 * H_DIM + h]
                 + shiftv[idx] * g_w1[(size_t)129 * H_DIM + h];
        #pragma unroll 8
        for (int e = 0; e < CE_DIM; ++e)
            bv = fmaf(gtab[(size_t)idx * CE_DIM + e], g_w1[(size_t)(65 + e) * H_DIM + h], bv);
        Bvg[(size_t)g * H_DIM + h] = bv;
    }
}

// ---------------------------------------------------------------------------
// K_main: one block per gene, 512 threads = 8 waves (2m x 4n wave grid).
// x1 build (+p reg-partials) -> MFMA (B dbuf) -> p-reduce -> q -> epilogue
// -> softmax.  LDS ~79.4 KB -> 2 blocks/CU.
// ---------------------------------------------------------------------------
__global__ __launch_bounds__(512, 4) void k_main(
    const float* __restrict__ ctrl, const int* __restrict__ gidx,
    const float* __restrict__ g_w1, const float* __restrict__ g_w2,
    const float* __restrict__ g_b2, const float* __restrict__ g_w3,
    const float* __restrict__ Atc, const float* __restrict__ Bvg,
    const unsigned short* __restrict__ w2abt, float* __restrict__ out)
{
    __shared__ __align__(16) unsigned short x1t[C_CELLS * LDAe];  // 66560 B
    __shared__ __align__(16) float scratch[8 * LDAe];             // pp, later red2 (8320 B)
    __shared__ __align__(16) float Bvl[H_DIM];                    // later qtmp
    __shared__ __align__(16) float w1l[H_DIM];                    // later pvec
    __shared__ float qv[H_DIM];
    __shared__ float w3v[H_DIM];
    __shared__ float cc[C_CELLS];
    __shared__ float wred[4];

    const int g = blockIdx.x;
    const int t = threadIdx.x;
    const int idx = gidx[g];

    const int lane = t & 63;
    const int w    = t >> 6;
    const int quad = lane >> 4;
    const int nlo  = lane & 15;
    const int wm   = w >> 2;      // rows [wm*64, +64)
    const int wn   = w & 3;       // cols [wn*64, +64)

    // prefetch kt=0 B-fragments (global, no dependences)
    const unsigned short* bbase = w2abt + (size_t)(wn * 64 + nlo) * H_DIM + quad * 8;
    short8 bcur[4];
    #pragma unroll
    for (int nt = 0; nt < 4; ++nt)
        bcur[nt] = *(const short8*)(bbase + (size_t)nt * 16 * H_DIM);

    if (t < C_CELLS) cc[t] = ctrl[(size_t)t * G_GENES + idx];
    if (t < H_DIM) {
        Bvl[t] = Bvg[(size_t)g * H_DIM + t];
        w1l[t] = g_w1[t];
        w3v[t] = g_w3[t];
    }
    __syncthreads();   // B0

    // ---- x1 build: thread = (h-octet ho = t&31, cell-group cgrp = t>>5) ----
    // 8 cells x 8 h per thread; p-partials accumulate in registers.
    {
        const int ho = t & 31, cgrp = t >> 5;
        const int h0 = ho * 8;
        float4 wv0 = *(const float4*)(w1l + h0);
        float4 wv1 = *(const float4*)(w1l + h0 + 4);
        float4 bv0 = *(const float4*)(Bvl + h0);
        float4 bv1 = *(const float4*)(Bvl + h0 + 4);
        float s[8];
        #pragma unroll
        for (int j = 0; j < 8; ++j) s[j] = 0.f;
        #pragma unroll
        for (int i = 0; i < 8; ++i) {
            const int c = cgrp * 8 + i;
            const float ccv = cc[c];
            float4 a0 = *(const float4*)(Atc + (size_t)c * H_DIM + h0);
            float4 a1 = *(const float4*)(Atc + (size_t)c * H_DIM + h0 + 4);
            float v0 = eluf(fmaf(ccv, wv0.x, a0.x + bv0.x));
            float v1 = eluf(fmaf(ccv, wv0.y, a0.y + bv0.y));
            float v2 = eluf(fmaf(ccv, wv0.z, a0.z + bv0.z));
            float v3 = eluf(fmaf(ccv, wv0.w, a0.w + bv0.w));
            float v4 = eluf(fmaf(ccv, wv1.x, a1.x + bv1.x));
            float v5 = eluf(fmaf(ccv, wv1.y, a1.y + bv1.y));
            float v6 = eluf(fmaf(ccv, wv1.z, a1.z + bv1.z));
            float v7 = eluf(fmaf(ccv, wv1.w, a1.w + bv1.w));
            s[0] += v0; s[1] += v1; s[2] += v2; s[3] += v3;
            s[4] += v4; s[5] += v5; s[6] += v6; s[7] += v7;
            uint4 pk;
            pk.x = (unsigned)f2bf(v0) | ((unsigned)f2bf(v1) << 16);
            pk.y = (unsigned)f2bf(v2) | ((unsigned)f2bf(v3) << 16);
            pk.z = (unsigned)f2bf(v4) | ((unsigned)f2bf(v5) << 16);
            pk.w = (unsigned)f2bf(v6) | ((unsigned)f2bf(v7) << 16);
            *(uint4*)&x1t[c * LDAe + h0] = pk;
        }
        // pair-reduce across the wave's two cell-groups, write wave partial
        #pragma unroll
        for (int j = 0; j < 8; ++j) s[j] += __shfl_xor(s[j], 32);
        if (lane < 32) {
            float4 p0 = {s[0], s[1], s[2], s[3]};
            float4 p1 = {s[4], s[5], s[6], s[7]};
            *(float4*)&scratch[w * LDAe + h0] = p0;
            *(float4*)&scratch[w * LDAe + h0 + 4] = p1;
        }
    }
    __syncthreads();   // B1: x1t + pp complete

    // ---- MFMA: 4mt x 4nt, K=256 in 8 steps, B-frags double-buffered ----
    floatx4 acc[4][4];
    #pragma unroll
    for (int mt = 0; mt < 4; ++mt)
        #pragma unroll
        for (int nt = 0; nt < 4; ++nt)
            acc[mt][nt] = (floatx4){0.f, 0.f, 0.f, 0.f};

    const unsigned short* abase = &x1t[(wm * 64 + nlo) * LDAe + quad * 8];

    #pragma unroll
    for (int kt = 0; kt < 8; ++kt) {
        short8 af[4];
        #pragma unroll
        for (int mt = 0; mt < 4; ++mt)
            af[mt] = *(const short8*)(abase + mt * 16 * LDAe + kt * 32);
        short8 bnx[4];
        if (kt < 7) {
            #pragma unroll
            for (int nt = 0; nt < 4; ++nt)
                bnx[nt] = *(const short8*)(bbase + (size_t)nt * 16 * H_DIM + (kt + 1) * 32);
        }
        #pragma unroll
        for (int nt = 0; nt < 4; ++nt)
            #pragma unroll
            for (int mt = 0; mt < 4; ++mt)
                acc[mt][nt] = __builtin_amdgcn_mfma_f32_16x16x32_bf16(af[mt], bcur[nt], acc[mt][nt], 0, 0, 0);
        if (kt < 7) {
            #pragma unroll
            for (int nt = 0; nt < 4; ++nt) bcur[nt] = bnx[nt];
        }
    }

    // ---- p-reduce: pvec (reuses w1l; build reads finished before B1) ----
    if (t < H_DIM) {
        float ps = 0.f;
        #pragma unroll
        for (int w2 = 0; w2 < 8; ++w2) ps += scratch[w2 * LDAe + t];
        w1l[t] = ps * (1.0f / 128.0f);
    }
    __syncthreads();   // B2: pvec ready

    // ---- q = p @ W2b + b2, fp32, 2-way split over h ----
    {
        const int j = t & 255, hf = t >> 8;
        float qp = 0.f;
        const float* w2b = g_w2 + (size_t)(H_DIM + hf * 128) * H_DIM + j;
        const float* pv = w1l + hf * 128;
        #pragma unroll 16
        for (int h = 0; h < 128; ++h) qp = fmaf(pv[h], w2b[(size_t)h * H_DIM], qp);
        if (hf) Bvl[j] = qp;       // qtmp (Bvl reads finished before B1)
        __syncthreads();           // B3
        if (!hf) qv[j] = qp + Bvl[j] + g_b2[j];
    }
    __syncthreads();   // B4: qv ready

    // ---- epilogue: logit partials (C/D: col=lane&15, row=quad*4+reg) ----
    float* red2 = scratch;         // pp consumed at p-reduce
    float qj[4], w3j[4];
    #pragma unroll
    for (int nt = 0; nt < 4; ++nt) {
        const int j = wn * 64 + nt * 16 + nlo;
        qj[nt] = qv[j];
        w3j[nt] = w3v[j];
    }
    #pragma unroll
    for (int mt = 0; mt < 4; ++mt) {
        #pragma unroll
        for (int reg = 0; reg < 4; ++reg) {
            float part = 0.f;
            #pragma unroll
            for (int nt = 0; nt < 4; ++nt)
                part = fmaf(eluf(acc[mt][nt][reg] + qj[nt]), w3j[nt], part);
            part += __shfl_xor(part, 1);
            part += __shfl_xor(part, 2);
            part += __shfl_xor(part, 4);
            part += __shfl_xor(part, 8);
            if (nlo == 0)
                red2[(wm * 64 + mt * 16 + quad * 4 + reg) * 5 + wn] = part;
        }
    }
    __syncthreads();   // B5: red2 complete

    // ---- softmax over 128 cells (waves 0-1, shuffle-based) ----
    float s = 0.f, e = 0.f;
    if (t < C_CELLS) {
        s = red2[t * 5 + 0] + red2[t * 5 + 1] + red2[t * 5 + 2] + red2[t * 5 + 3];
        float m = s;
        #pragma unroll
        for (int off = 1; off < 64; off <<= 1) m = fmaxf(m, __shfl_xor(m, off));
        if (lane == 0) wred[w] = m;
    }
    __syncthreads();   // B6
    if (t < C_CELLS) {
        const float m = fmaxf(wred[0], wred[1]);
        e = __expf(s - m);
        float S = e;
        #pragma unroll
        for (int off = 1; off < 64; off <<= 1) S += __shfl_xor(S, off);
        if (lane == 0) wred[2 + w] = S;
    }
    __syncthreads();   // B7
    if (t < C_CELLS) out[(size_t)t * G_GENES + g] = e / (wred[2] + wred[3]);
}

// ---------------------------------------------------------------------------
extern "C" void kernel_launch(void* const* d_in, const int* in_sizes, int n_in,
                              void* d_out, int out_size, void* d_ws, size_t ws_size,
                              hipStream_t stream) {
    const float* ctrl   = (const float*)d_in[0];
    const float* shiftv = (const float*)d_in[1];
    const int*   gidx   = (const int*)d_in[2];
    const float* ce_w1  = (const float*)d_in[3];
    const float* ce_b1  = (const float*)d_in[4];
    const float* ce_w2  = (const float*)d_in[5];
    const float* ce_b2  = (const float*)d_in[6];
    const float* gtab   = (const float*)d_in[7];
    const float* g_w1   = (const float*)d_in[8];
    const float* g_b1   = (const float*)d_in[9];
    const float* g_w2   = (const float*)d_in[10];
    const float* g_b2   = (const float*)d_in[11];
    const float* g_w3   = (const float*)d_in[12];
    // g_b3 and the p2@w3b term are per-gene constants: cancel in softmax.

    // workspace: Atc 128K | w2abt 128K | Bvg 2M
    char* ws = (char*)d_ws;
    float* Atc            = (float*)(ws);
    unsigned short* w2abt = (unsigned short*)(ws + 128 * 1024);
    float* Bvg            = (float*)(ws + 256 * 1024);
    float* out            = (float*)d_out;

    k_prep<<<C_CELLS + 8 + G_GENES / 4, 1024, 0, stream>>>(
        ctrl, ce_w1, ce_b1, ce_w2, ce_b2, g_w1, g_b1, shiftv, gidx, gtab, g_w2,
        Atc, w2abt, Bvg);
    k_main<<<G_GENES, 512, 0, stream>>>(ctrl, gidx, g_w1, g_w2, g_b2, g_w3,
                                        Atc, Bvg, w2abt, out);
}